// Round 5
// baseline (414.867 us; speedup 1.0000x reference)
//
#include <hip/hip_runtime.h>
#include <stdint.h>

typedef __attribute__((ext_vector_type(8))) short short8;
typedef __attribute__((ext_vector_type(4))) float f32x4;
typedef unsigned short u16;
typedef unsigned int u32;

#define NSIG   16
#define NPER   4096
#define DIN    256
#define DMODEL 1024
#define NB     16
#define NL     4096
#define LP1    4097
#define LDK32  40   // bf16 row stride: 80B rows -> 16B-aligned b128 reads, 2-way alias (free)

// ---------------------------------------------------------------------------
// Fused: f32 -> reg prefetch -> bf16 LDS (BK=32) -> MFMA -> scatter epilogue
// + attn_keep/CLS tail.  grid = 4096 x 256.  LDS = 20.0 KB -> 8 blocks/CU.
// ---------------------------------------------------------------------------
__global__ __launch_bounds__(256, 6)
void enc_fused(const float* __restrict__ emb,     // [65536][256] f32
               const int* __restrict__ eidx,
               const int* __restrict__ pos,
               const int* __restrict__ sid,
               const int* __restrict__ mod_,
               const int* __restrict__ role,
               const unsigned char* __restrict__ pmask,
               const float* __restrict__ Wp,      // [16][1024][256] f32
               const float* __restrict__ bp,
               const float* __restrict__ cls,
               const float* __restrict__ pos_t,
               const float* __restrict__ id_t,
               const float* __restrict__ mod_t,
               const float* __restrict__ role_t,
               float* __restrict__ out)
{
    __shared__ u16 Ab[128 * LDK32];   // 10.0 KB
    __shared__ u16 Bb[128 * LDK32];   // 10.0 KB

    // XCD-chunked bijective swizzle (4096 % 8 == 0)
    const int bid = blockIdx.x;
    const int lg = (bid & 7) * 512 + (bid >> 3);
    const int rowBase = (lg >> 3) * 128;
    const int colBase = (lg & 7) * 128;
    const int s = rowBase >> 12;

    const int t = threadIdx.x;
    const int lane = t & 63;
    const int w = t >> 6;
    const int wr = w >> 1, wc = w & 1;
    const int l4 = lane >> 4;

    f32x4 acc[4][4] = {};

    // staging map: thread t -> row r0 + p*32, float col c4f (4-wide), 8 chunks/row
    const int r0 = t >> 3;            // 0..31
    const int c4f = (t & 7) * 4;      // 0,4,..,28

    const float* Ag = emb + (size_t)rowBase * DIN;
    const float* Bg = Wp + ((size_t)s * DMODEL + colBase) * DIN;

    // ---- prologue: k-tile 0 into registers ----
    float4 rA[4], rB[4];
    #pragma unroll
    for (int p = 0; p < 4; ++p) {
        const int r = p * 32 + r0;
        rA[p] = *(const float4*)(Ag + (size_t)r * DIN + c4f);
        rB[p] = *(const float4*)(Bg + (size_t)r * DIN + c4f);
    }

    for (int kk = 0; kk < DIN; kk += 32) {
        // ---- pack current regs -> LDS (proven pack math) ----
        #pragma unroll
        for (int p = 0; p < 4; ++p) {
            const int r = p * 32 + r0;
            const float4 va = rA[p];
            const float4 vb = rB[p];
            uint2 pa, pb;
            pa.x = (__builtin_bit_cast(u32, va.x) >> 16) | (__builtin_bit_cast(u32, va.y) & 0xFFFF0000u);
            pa.y = (__builtin_bit_cast(u32, va.z) >> 16) | (__builtin_bit_cast(u32, va.w) & 0xFFFF0000u);
            pb.x = (__builtin_bit_cast(u32, vb.x) >> 16) | (__builtin_bit_cast(u32, vb.y) & 0xFFFF0000u);
            pb.y = (__builtin_bit_cast(u32, vb.z) >> 16) | (__builtin_bit_cast(u32, vb.w) & 0xFFFF0000u);
            *(uint2*)&Ab[r * LDK32 + c4f] = pa;
            *(uint2*)&Bb[r * LDK32 + c4f] = pb;
        }
        __syncthreads();

        // ---- issue next k-tile loads ----
        if (kk + 32 < DIN) {
            #pragma unroll
            for (int p = 0; p < 4; ++p) {
                const int r = p * 32 + r0;
                rA[p] = *(const float4*)(Ag + (size_t)r * DIN + kk + 32 + c4f);
                rB[p] = *(const float4*)(Bg + (size_t)r * DIN + kk + 32 + c4f);
            }
        }

        // ---- MFMA: one K=32 step (proven fragment pattern) ----
        {
            const int ko = l4 * 8;
            short8 af[4], bf[4];
            #pragma unroll
            for (int m = 0; m < 4; ++m)
                af[m] = *(const short8*)&Ab[(wr * 64 + m * 16 + (lane & 15)) * LDK32 + ko];
            #pragma unroll
            for (int n = 0; n < 4; ++n)
                bf[n] = *(const short8*)&Bb[(wc * 64 + n * 16 + (lane & 15)) * LDK32 + ko];
            #pragma unroll
            for (int m = 0; m < 4; ++m) {
                #pragma unroll
                for (int n = 0; n < 4; ++n)
                    acc[m][n] = __builtin_amdgcn_mfma_f32_16x16x32_bf16(
                        af[m], bf[n], acc[m][n], 0, 0, 0);
            }
        }
        __syncthreads();
    }

    // ---- epilogue (proven): bias + 4 gathers + mask + scatter ----
    const int cb = colBase + wc * 64 + (lane & 15);
    float bpv[4];
    #pragma unroll
    for (int n = 0; n < 4; ++n) bpv[n] = bp[s * DMODEL + cb + n * 16];

    #pragma unroll
    for (int m = 0; m < 4; ++m) {
        #pragma unroll
        for (int j = 0; j < 4; ++j) {
            const int gr = rowBase + wr * 64 + m * 16 + l4 * 4 + j;
            const int idx = eidx[gr];
            const int p_ = pos[idx];
            const int si = sid[idx];
            const int mo = mod_[idx];
            const int ro = role[idx];
            const int pm = pmask[idx];
            const size_t orow =
                ((size_t)(idx >> 12) * LP1 + 1 + (size_t)(idx & 4095)) * DMODEL;
            #pragma unroll
            for (int n = 0; n < 4; ++n) {
                const int col = cb + n * 16;
                float v = acc[m][n][j] + bpv[n]
                        + pos_t[(size_t)p_ * DMODEL + col]
                        + id_t[si * DMODEL + col]
                        + mod_t[mo * DMODEL + col]
                        + role_t[ro * DMODEL + col];
                v = pm ? 0.0f : v;
                __builtin_nontemporal_store(v, &out[orow + col]);
            }
        }
    }

    // ---- aux tail: attn_keep + CLS rows (blocks 0..256 only do real work) ----
    const int gid = bid * 256 + t;
    if (gid < NB * LP1) {
        const size_t OUT_TOK = (size_t)NB * LP1 * DMODEL;
        const int b = gid / LP1;
        const int r = gid - b * LP1;
        float keep = 1.0f;
        if (r > 0) keep = pmask[b * NL + r - 1] ? 0.0f : 1.0f;
        out[OUT_TOK + gid] = keep;
    }
    if (gid < NB * DMODEL) {
        const int b = gid >> 10;
        const int e = gid & (DMODEL - 1);
        out[(size_t)b * LP1 * DMODEL + e] = cls[e];
    }
}

extern "C" void kernel_launch(void* const* d_in, const int* in_sizes, int n_in,
                              void* d_out, int out_size, void* d_ws, size_t ws_size,
                              hipStream_t stream)
{
    (void)in_sizes; (void)n_in; (void)out_size; (void)d_ws; (void)ws_size;
    const float*         emb    = (const float*)d_in[0];
    const int*           eidx   = (const int*)d_in[1];
    const int*           pos    = (const int*)d_in[2];
    const int*           sid    = (const int*)d_in[3];
    const int*           mod_   = (const int*)d_in[4];
    const int*           role   = (const int*)d_in[5];
    const unsigned char* pmask  = (const unsigned char*)d_in[6];
    const float*         Wp     = (const float*)d_in[7];
    const float*         bp     = (const float*)d_in[8];
    const float*         cls    = (const float*)d_in[9];
    const float*         pos_t  = (const float*)d_in[10];
    const float*         id_t   = (const float*)d_in[11];
    const float*         mod_t  = (const float*)d_in[12];
    const float*         role_t = (const float*)d_in[13];
    float* out = (float*)d_out;

    enc_fused<<<4096, 256, 0, stream>>>(emb, eidx, pos, sid, mod_, role, pmask,
                                        Wp, bp, cls, pos_t, id_t, mod_t, role_t, out);
}

// Round 7
// 130.006 us; speedup vs baseline: 3.1912x; 3.1912x over previous
//
#include <hip/hip_runtime.h>
#include <stdint.h>

typedef __attribute__((ext_vector_type(8))) short short8;
typedef __attribute__((ext_vector_type(4))) float f32x4;
typedef unsigned short u16;
typedef unsigned int u32;

#define NSIG   16
#define NPER   4096
#define DIN    256
#define DMODEL 1024
#define NB     16
#define NL     4096
#define LP1    4097
#define LDK32  40   // bf16 row stride: 80B rows -> 16B-aligned b128 reads

// ---------------------------------------------------------------------------
// Fused: f32 -> reg prefetch -> bf16 LDS (BK=32) -> MFMA -> scatter epilogue
// + attn_keep/CLS tail.  grid = 4096 x 256.  LDS = 20.0 KB.
// Identical to round-5 (correctness-proven, absmax 0.0625) EXCEPT
// __launch_bounds__(256,4): 128-VGPR cap >> ~84 demand -> no spills.
// (round-5's (256,6) capped at 85 VGPR -> acc spilled to scratch -> 1.3 GB
//  scratch writes, 415 us.  VGPR_Count is the tripwire: expect ~80-100.)
// ---------------------------------------------------------------------------
__global__ __launch_bounds__(256, 4)
void enc_fused(const float* __restrict__ emb,     // [65536][256] f32
               const int* __restrict__ eidx,
               const int* __restrict__ pos,
               const int* __restrict__ sid,
               const int* __restrict__ mod_,
               const int* __restrict__ role,
               const unsigned char* __restrict__ pmask,
               const float* __restrict__ Wp,      // [16][1024][256] f32
               const float* __restrict__ bp,
               const float* __restrict__ cls,
               const float* __restrict__ pos_t,
               const float* __restrict__ id_t,
               const float* __restrict__ mod_t,
               const float* __restrict__ role_t,
               float* __restrict__ out)
{
    __shared__ u16 Ab[128 * LDK32];   // 10.0 KB
    __shared__ u16 Bb[128 * LDK32];   // 10.0 KB

    // XCD-chunked bijective swizzle (4096 % 8 == 0)
    const int bid = blockIdx.x;
    const int lg = (bid & 7) * 512 + (bid >> 3);
    const int rowBase = (lg >> 3) * 128;
    const int colBase = (lg & 7) * 128;
    const int s = rowBase >> 12;

    const int t = threadIdx.x;
    const int lane = t & 63;
    const int w = t >> 6;
    const int wr = w >> 1, wc = w & 1;
    const int l4 = lane >> 4;

    f32x4 acc[4][4] = {};

    // staging map: thread t -> rows r0+p*32, float col c4f (float4-wide)
    const int r0 = t >> 3;            // 0..31
    const int c4f = (t & 7) * 4;      // 0,4,..,28

    const float* Ag = emb + (size_t)rowBase * DIN;
    const float* Bg = Wp + ((size_t)s * DMODEL + colBase) * DIN;

    // ---- prologue: k-tile 0 into registers ----
    float4 rA[4], rB[4];
    #pragma unroll
    for (int p = 0; p < 4; ++p) {
        const int r = p * 32 + r0;
        rA[p] = *(const float4*)(Ag + (size_t)r * DIN + c4f);
        rB[p] = *(const float4*)(Bg + (size_t)r * DIN + c4f);
    }

    for (int kk = 0; kk < DIN; kk += 32) {
        // ---- pack current regs -> LDS (proven pack math) ----
        #pragma unroll
        for (int p = 0; p < 4; ++p) {
            const int r = p * 32 + r0;
            const float4 va = rA[p];
            const float4 vb = rB[p];
            uint2 pa, pb;
            pa.x = (__builtin_bit_cast(u32, va.x) >> 16) | (__builtin_bit_cast(u32, va.y) & 0xFFFF0000u);
            pa.y = (__builtin_bit_cast(u32, va.z) >> 16) | (__builtin_bit_cast(u32, va.w) & 0xFFFF0000u);
            pb.x = (__builtin_bit_cast(u32, vb.x) >> 16) | (__builtin_bit_cast(u32, vb.y) & 0xFFFF0000u);
            pb.y = (__builtin_bit_cast(u32, vb.z) >> 16) | (__builtin_bit_cast(u32, vb.w) & 0xFFFF0000u);
            *(uint2*)&Ab[r * LDK32 + c4f] = pa;
            *(uint2*)&Bb[r * LDK32 + c4f] = pb;
        }
        __syncthreads();

        // ---- issue next k-tile loads (hide under MFMA) ----
        if (kk + 32 < DIN) {
            #pragma unroll
            for (int p = 0; p < 4; ++p) {
                const int r = p * 32 + r0;
                rA[p] = *(const float4*)(Ag + (size_t)r * DIN + kk + 32 + c4f);
                rB[p] = *(const float4*)(Bg + (size_t)r * DIN + kk + 32 + c4f);
            }
        }

        // ---- MFMA: one K=32 step (proven fragment pattern) ----
        {
            const int ko = l4 * 8;
            short8 af[4], bf[4];
            #pragma unroll
            for (int m = 0; m < 4; ++m)
                af[m] = *(const short8*)&Ab[(wr * 64 + m * 16 + (lane & 15)) * LDK32 + ko];
            #pragma unroll
            for (int n = 0; n < 4; ++n)
                bf[n] = *(const short8*)&Bb[(wc * 64 + n * 16 + (lane & 15)) * LDK32 + ko];
            #pragma unroll
            for (int m = 0; m < 4; ++m) {
                #pragma unroll
                for (int n = 0; n < 4; ++n)
                    acc[m][n] = __builtin_amdgcn_mfma_f32_16x16x32_bf16(
                        af[m], bf[n], acc[m][n], 0, 0, 0);
            }
        }
        __syncthreads();
    }

    // ---- epilogue (proven): bias + 4 gathers + mask + scatter ----
    const int cb = colBase + wc * 64 + (lane & 15);
    float bpv[4];
    #pragma unroll
    for (int n = 0; n < 4; ++n) bpv[n] = bp[s * DMODEL + cb + n * 16];

    #pragma unroll
    for (int m = 0; m < 4; ++m) {
        #pragma unroll
        for (int j = 0; j < 4; ++j) {
            const int gr = rowBase + wr * 64 + m * 16 + l4 * 4 + j;
            const int idx = eidx[gr];
            const int p_ = pos[idx];
            const int si = sid[idx];
            const int mo = mod_[idx];
            const int ro = role[idx];
            const int pm = pmask[idx];
            const size_t orow =
                ((size_t)(idx >> 12) * LP1 + 1 + (size_t)(idx & 4095)) * DMODEL;
            #pragma unroll
            for (int n = 0; n < 4; ++n) {
                const int col = cb + n * 16;
                float v = acc[m][n][j] + bpv[n]
                        + pos_t[(size_t)p_ * DMODEL + col]
                        + id_t[si * DMODEL + col]
                        + mod_t[mo * DMODEL + col]
                        + role_t[ro * DMODEL + col];
                v = pm ? 0.0f : v;
                __builtin_nontemporal_store(v, &out[orow + col]);
            }
        }
    }

    // ---- aux tail (proven): attn_keep + CLS rows ----
    const int gid = bid * 256 + t;
    if (gid < NB * LP1) {
        const size_t OUT_TOK = (size_t)NB * LP1 * DMODEL;
        const int b = gid / LP1;
        const int r = gid - b * LP1;
        float keep = 1.0f;
        if (r > 0) keep = pmask[b * NL + r - 1] ? 0.0f : 1.0f;
        out[OUT_TOK + gid] = keep;
    }
    if (gid < NB * DMODEL) {
        const int b = gid >> 10;
        const int e = gid & (DMODEL - 1);
        out[(size_t)b * LP1 * DMODEL + e] = cls[e];
    }
}

extern "C" void kernel_launch(void* const* d_in, const int* in_sizes, int n_in,
                              void* d_out, int out_size, void* d_ws, size_t ws_size,
                              hipStream_t stream)
{
    (void)in_sizes; (void)n_in; (void)out_size; (void)d_ws; (void)ws_size;
    const float*         emb    = (const float*)d_in[0];
    const int*           eidx   = (const int*)d_in[1];
    const int*           pos    = (const int*)d_in[2];
    const int*           sid    = (const int*)d_in[3];
    const int*           mod_   = (const int*)d_in[4];
    const int*           role   = (const int*)d_in[5];
    const unsigned char* pmask  = (const unsigned char*)d_in[6];
    const float*         Wp     = (const float*)d_in[7];
    const float*         bp     = (const float*)d_in[8];
    const float*         cls    = (const float*)d_in[9];
    const float*         pos_t  = (const float*)d_in[10];
    const float*         id_t   = (const float*)d_in[11];
    const float*         mod_t  = (const float*)d_in[12];
    const float*         role_t = (const float*)d_in[13];
    float* out = (float*)d_out;

    enc_fused<<<4096, 256, 0, stream>>>(emb, eidx, pos, sid, mod_, role, pmask,
                                        Wp, bp, cls, pos_t, id_t, mod_t, role_t, out);
}